// Round 1
// baseline (3558.730 us; speedup 1.0000x reference)
//
#include <hip/hip_runtime.h>
#include <hip/hip_bf16.h>

#define NFREQ   12
#define TP      16          // points per block
#define HSTRIDE 260         // f32 per point row in LDS (16B-aligned stride, holds max 256)
#define PI_F    3.14159265358979323846f

// Dense layer: reads h[tp][0..K), writes h[tp][0..NCOLS) (optionally ReLU).
// 128 threads; JT=2 columns per thread. If NCOLS<256, threads split into
// groups each owning a slice of the TP points.
template<int K, int LDW, int NCOLS, bool RELU>
__device__ __forceinline__ void dense_layer(float (*h)[HSTRIDE],
                                            const float* __restrict__ W,
                                            const float* __restrict__ bias,
                                            int t)
{
    constexpr int TCOLS = NCOLS / 2;      // threads per group
    constexpr int NG    = 128 / TCOLS;    // point-groups
    constexpr int TPG   = TP / NG;        // points per group
    constexpr int KT4   = K / 4;
    constexpr int KREM  = K - KT4 * 4;

    const int g   = t / TCOLS;
    const int tl  = t - g * TCOLS;
    const int j   = 2 * tl;               // local column pair
    const int tp0 = g * TPG;

    float b0 = bias[j], b1 = bias[j + 1];
    float acc[TPG][2];
#pragma unroll
    for (int p = 0; p < TPG; ++p) { acc[p][0] = b0; acc[p][1] = b1; }

    const float* wp = W + j;
    for (int kt = 0; kt < KT4; ++kt) {
        const int k = kt * 4;
        float w00 = wp[0 * LDW], w01 = wp[0 * LDW + 1];
        float w10 = wp[1 * LDW], w11 = wp[1 * LDW + 1];
        float w20 = wp[2 * LDW], w21 = wp[2 * LDW + 1];
        float w30 = wp[3 * LDW], w31 = wp[3 * LDW + 1];
#pragma unroll
        for (int p = 0; p < TPG; ++p) {
            float4 hv = *reinterpret_cast<const float4*>(&h[tp0 + p][k]);
            acc[p][0] = fmaf(hv.x, w00, acc[p][0]); acc[p][1] = fmaf(hv.x, w01, acc[p][1]);
            acc[p][0] = fmaf(hv.y, w10, acc[p][0]); acc[p][1] = fmaf(hv.y, w11, acc[p][1]);
            acc[p][0] = fmaf(hv.z, w20, acc[p][0]); acc[p][1] = fmaf(hv.z, w21, acc[p][1]);
            acc[p][0] = fmaf(hv.w, w30, acc[p][0]); acc[p][1] = fmaf(hv.w, w31, acc[p][1]);
        }
        wp += 4 * LDW;
    }
    if constexpr (KREM > 0) {
#pragma unroll
        for (int r = 0; r < KREM; ++r) {
            float wr0 = wp[r * LDW], wr1 = wp[r * LDW + 1];
#pragma unroll
            for (int p = 0; p < TPG; ++p) {
                float hv = h[tp0 + p][KT4 * 4 + r];
                acc[p][0] = fmaf(hv, wr0, acc[p][0]);
                acc[p][1] = fmaf(hv, wr1, acc[p][1]);
            }
        }
    }

    __syncthreads();   // everyone done reading h
#pragma unroll
    for (int p = 0; p < TPG; ++p) {
        float a0 = acc[p][0], a1 = acc[p][1];
        if (RELU) { a0 = fmaxf(a0, 0.f); a1 = fmaxf(a1, 0.f); }
        *reinterpret_cast<float2*>(&h[tp0 + p][j]) = make_float2(a0, a1);
    }
    __syncthreads();   // h ready for next layer
}

__global__ __launch_bounds__(128, 4)
void ffmlp_kernel(const float* __restrict__ mean,
                  const float* __restrict__ cov,
                  const float* __restrict__ Wd_in,  const float* __restrict__ bd_in,
                  const float* __restrict__ Wd_hid, const float* __restrict__ bd_hid,
                  const float* __restrict__ Wd_out, const float* __restrict__ bd_out,
                  const float* __restrict__ Wc_in,  const float* __restrict__ bc_in,
                  const float* __restrict__ Wc_hid, const float* __restrict__ bc_hid,
                  const float* __restrict__ Wc_out, const float* __restrict__ bc_out,
                  const int* __restrict__ decayscale,
                  float* __restrict__ out, int N)
{
    __shared__ float h[TP][HSTRIDE];
    __shared__ float dval[TP];

    const int t  = threadIdx.x;
    const int p0 = blockIdx.x * TP;
    const float decay = (float)(*decayscale);

    // ---- Fourier embedding: 8 threads per point, (f,d) pairs ----
    {
        const int tp = t >> 3, q = t & 7;
        const long pt = (long)p0 + tp;
        if (pt < N) {
            if (q == 0) {
                h[tp][0] = mean[pt * 3 + 0];
                h[tp][1] = mean[pt * 3 + 1];
                h[tp][2] = mean[pt * 3 + 2];
                h[tp][75] = 0.f;
            }
#pragma unroll
            for (int i = 0; i < 5; ++i) {
                const int p = q + 8 * i;        // covers 0..39, use <36
                if (p < 36) {
                    const int f = p / 3, d = p - 3 * f;
                    const float xd  = mean[pt * 3 + d];
                    const float var = cov[pt * 9 + 4 * d];   // diag element
                    const float fs  = (float)(1u << f);
                    const float xb  = xd * fs;
                    const float vb  = var * fs * fs;
                    const float wcl = fminf(fmaxf(decay - (float)f, 0.f), 1.f);
                    const float win = 0.5f * (1.f - cosf(wcl * PI_F));
                    const float att = expf(-0.5f * vb) * win;
                    float s, c;
                    sincosf(xb, &s, &c);
                    h[tp][3 + 6 * f + d] = s * att;
                    h[tp][6 + 6 * f + d] = c * att;
                }
            }
        }
    }
    __syncthreads();

    // ---- density MLP ----
    dense_layer<75, 256, 256, true>(h, Wd_in, bd_in, t);
    for (int i = 0; i < 6; ++i)
        dense_layer<256, 256, 256, true>(h, Wd_hid + i * 65536, bd_hid + i * 256, t);

    // density scalar d = h . Wd_out[:,0] + bd_out[0]  (wave 0 only; reads h, no write)
    if (t < 64) {
        const int tp = t >> 2, q = t & 3;
        float s = 0.f;
        for (int k = 64 * q; k < 64 * q + 64; k += 4) {
            float4 hv = *reinterpret_cast<const float4*>(&h[tp][k]);
            s = fmaf(hv.x, Wd_out[(k + 0) * 257], s);
            s = fmaf(hv.y, Wd_out[(k + 1) * 257], s);
            s = fmaf(hv.z, Wd_out[(k + 2) * 257], s);
            s = fmaf(hv.w, Wd_out[(k + 3) * 257], s);
        }
        s += __shfl_xor(s, 1);
        s += __shfl_xor(s, 2);
        if (q == 0) dval[tp] = s + bd_out[0];
    }

    // features = (h @ Wd_out + bd_out)[:, 1:257]   (no relu)
    dense_layer<256, 257, 256, false>(h, Wd_out + 1, bd_out + 1, t);

    // ---- color MLP ----
    dense_layer<256, 128, 128, true>(h, Wc_in, bc_in, t);
    for (int i = 0; i < 2; ++i)
        dense_layer<128, 128, 128, true>(h, Wc_hid + i * 16384, bc_hid + i * 128, t);

    // ---- output: rgb (3 cols) + d ----
    if (t < 48) {
        const int tp = t / 3, c = t - 3 * (t / 3);
        const long pt = (long)p0 + tp;
        float acc = bc_out[c];
        for (int k = 0; k < 128; k += 4) {
            float4 hv = *reinterpret_cast<const float4*>(&h[tp][k]);
            acc = fmaf(hv.x, Wc_out[(k + 0) * 3 + c], acc);
            acc = fmaf(hv.y, Wc_out[(k + 1) * 3 + c], acc);
            acc = fmaf(hv.z, Wc_out[(k + 2) * 3 + c], acc);
            acc = fmaf(hv.w, Wc_out[(k + 3) * 3 + c], acc);
        }
        if (pt < N) out[pt * 4 + c] = acc;
    } else if (t >= 64 && t < 64 + TP) {
        const int tp = t - 64;
        const long pt = (long)p0 + tp;
        if (pt < N) out[pt * 4 + 3] = dval[tp];
    }
}

extern "C" void kernel_launch(void* const* d_in, const int* in_sizes, int n_in,
                              void* d_out, int out_size, void* d_ws, size_t ws_size,
                              hipStream_t stream)
{
    const float* mean   = (const float*)d_in[0];
    const float* cov    = (const float*)d_in[1];
    const float* Wd_in  = (const float*)d_in[2];
    const float* bd_in  = (const float*)d_in[3];
    const float* Wd_hid = (const float*)d_in[4];
    const float* bd_hid = (const float*)d_in[5];
    const float* Wd_out = (const float*)d_in[6];
    const float* bd_out = (const float*)d_in[7];
    const float* Wc_in  = (const float*)d_in[8];
    const float* bc_in  = (const float*)d_in[9];
    const float* Wc_hid = (const float*)d_in[10];
    const float* bc_hid = (const float*)d_in[11];
    const float* Wc_out = (const float*)d_in[12];
    const float* bc_out = (const float*)d_in[13];
    const int*   decay  = (const int*)d_in[14];

    const int N = in_sizes[0] / 3;               // 262144 points
    const int blocks = (N + TP - 1) / TP;

    ffmlp_kernel<<<blocks, 128, 0, stream>>>(mean, cov,
                                             Wd_in, bd_in, Wd_hid, bd_hid,
                                             Wd_out, bd_out,
                                             Wc_in, bc_in, Wc_hid, bc_hid,
                                             Wc_out, bc_out,
                                             decay, (float*)d_out, N);
}

// Round 2
// 538.117 us; speedup vs baseline: 6.6133x; 6.6133x over previous
//
#include <hip/hip_runtime.h>
#include <hip/hip_bf16.h>

#define PI_F 3.14159265358979323846f
#define KPAD 264               // LDS activation row stride in fp16 elems (528 B)

typedef _Float16 h8 __attribute__((ext_vector_type(8)));
typedef _Float16 h4 __attribute__((ext_vector_type(4)));
typedef float f32x16 __attribute__((ext_vector_type(16)));

// ---- d_ws layout (fp16 elems) ----
// WT arrays are TRANSPOSED: WT[n][k], k padded to tile multiple.
#define OFF_DIN   0          // [256][96]
#define OFF_DHID  24576      // 6 x [256][256]
#define OFF_DOUT  417792     // [288][256]: n<256 -> Wd_out[k][n+1]; n==256 -> Wd_out[k][0]; else 0
#define OFF_CIN   491520     // [128][256]
#define OFF_CHID  524288     // 2 x [128][128]
#define OFF_COUT  557056     // [32][128]: n<3 -> Wc_out[k][n]; else 0
#define W_TOTAL   561152
// f32 biases appended after weights (byte off 1122304, 16B aligned)
#define B_DIN  0
#define B_DHID 256           // 6 x 256
#define B_FEAT 1792          // 288: n<256 -> bd_out[n+1]; n==256 -> bd_out[0]; else 0
#define B_CIN  2080          // 128
#define B_CHID 2208          // 2 x 128
#define B_TOTAL 2464
#define PREP_TOTAL (W_TOTAL + B_TOTAL)

__global__ void prep_kernel(const float* __restrict__ Wd_in,  const float* __restrict__ Wd_hid,
                            const float* __restrict__ Wd_out, const float* __restrict__ Wc_in,
                            const float* __restrict__ Wc_hid, const float* __restrict__ Wc_out,
                            const float* __restrict__ bd_in,  const float* __restrict__ bd_hid,
                            const float* __restrict__ bd_out, const float* __restrict__ bc_in,
                            const float* __restrict__ bc_hid,
                            _Float16* __restrict__ wdst, float* __restrict__ bdst)
{
    int i = blockIdx.x * 256 + threadIdx.x;
    if (i >= PREP_TOTAL) return;
    if (i < W_TOTAL) {
        float v = 0.f;
        if (i < OFF_DHID)      { int n = i / 96, k = i % 96; if (k < 75) v = Wd_in[k * 256 + n]; }
        else if (i < OFF_DOUT) { int j = i - OFF_DHID; int l = j / 65536, rem = j % 65536;
                                 int n = rem / 256, k = rem % 256; v = Wd_hid[(l * 256 + k) * 256 + n]; }
        else if (i < OFF_CIN)  { int j = i - OFF_DOUT; int n = j / 256, k = j % 256;
                                 if (n < 256) v = Wd_out[k * 257 + n + 1];
                                 else if (n == 256) v = Wd_out[k * 257]; }
        else if (i < OFF_CHID) { int j = i - OFF_CIN; int n = j / 256, k = j % 256; v = Wc_in[k * 128 + n]; }
        else if (i < OFF_COUT) { int j = i - OFF_CHID; int l = j / 16384, rem = j % 16384;
                                 int n = rem / 128, k = rem % 128; v = Wc_hid[(l * 128 + k) * 128 + n]; }
        else                   { int j = i - OFF_COUT; int n = j / 128, k = j % 128;
                                 if (n < 3) v = Wc_out[k * 3 + n]; }
        wdst[i] = (_Float16)v;
    } else {
        int b = i - W_TOTAL;
        float v = 0.f;
        if (b < B_DHID)      v = bd_in[b];
        else if (b < B_FEAT) v = bd_hid[b - B_DHID];
        else if (b < B_CIN)  { int n = b - B_FEAT;
                               if (n < 256) v = bd_out[n + 1]; else if (n == 256) v = bd_out[0]; }
        else if (b < B_CHID) v = bc_in[b - B_CIN];
        else                 v = bc_hid[b - B_CHID];
        bdst[b] = v;
    }
}

// One dense layer via 32x32x16 f16 MFMA.
// Wave (r,c): owns rows rbase..rbase+63 (2 mtiles), cols nbase..nbase+NT*32-1.
// A-operand = WT[n][k] tile (n rows), B-operand = At[m][k] tile (m cols).
// D[n][m]: col = lane&31 = m-local; row = (reg&3)+8*(reg>>2)+4*(lane>>5).
template<int KT, int NT, bool RELU, int WK>
__device__ __forceinline__ void dense(_Float16 (*At)[KPAD],
                                      const _Float16* __restrict__ WT,
                                      const float* __restrict__ bias,
                                      int rbase, int nbase, int lrow, int lq,
                                      bool dflag, float* dval, float dbias)
{
    f32x16 acc[2][NT];
    f32x16 accd[2];
#pragma unroll
    for (int mt = 0; mt < 2; ++mt) {
#pragma unroll
        for (int nt = 0; nt < NT; ++nt)
#pragma unroll
            for (int j = 0; j < 16; ++j) acc[mt][nt][j] = 0.f;
#pragma unroll
        for (int j = 0; j < 16; ++j) accd[mt][j] = 0.f;
    }

    const _Float16* wbase = WT + (size_t)(nbase + lrow) * WK + lq * 8;
    const _Float16* wdrow = WT + (size_t)(256 + lrow) * WK + lq * 8;   // FEAT extra ntile (rows 256..287)

#pragma unroll 2
    for (int kt = 0; kt < KT; ++kt) {
        const int koff = kt * 16 + lq * 8;
        h8 wf[NT];
#pragma unroll
        for (int nt = 0; nt < NT; ++nt)
            wf[nt] = *(const h8*)(wbase + (size_t)nt * 32 * WK + kt * 16);
        h8 wfd;
        if (dflag) wfd = *(const h8*)(wdrow + kt * 16);
#pragma unroll
        for (int mt = 0; mt < 2; ++mt) {
            h8 af = *(const h8*)(&At[rbase + mt * 32 + lrow][koff]);
#pragma unroll
            for (int nt = 0; nt < NT; ++nt)
                acc[mt][nt] = __builtin_amdgcn_mfma_f32_32x32x16_f16(wf[nt], af, acc[mt][nt], 0, 0, 0);
            if (dflag)
                accd[mt] = __builtin_amdgcn_mfma_f32_32x32x16_f16(wfd, af, accd[mt], 0, 0, 0);
        }
    }

    __syncthreads();   // all reads of At done

#pragma unroll
    for (int mt = 0; mt < 2; ++mt) {
        const int m = rbase + mt * 32 + lrow;
#pragma unroll
        for (int nt = 0; nt < NT; ++nt) {
#pragma unroll
            for (int p = 0; p < 4; ++p) {
                const int n0 = nbase + nt * 32 + p * 8 + lq * 4;
                float4 bv = *(const float4*)(bias + n0);
                float a0 = acc[mt][nt][4 * p + 0] + bv.x;
                float a1 = acc[mt][nt][4 * p + 1] + bv.y;
                float a2 = acc[mt][nt][4 * p + 2] + bv.z;
                float a3 = acc[mt][nt][4 * p + 3] + bv.w;
                if (RELU) {
                    a0 = fmaxf(a0, 0.f); a1 = fmaxf(a1, 0.f);
                    a2 = fmaxf(a2, 0.f); a3 = fmaxf(a3, 0.f);
                }
                h4 hv;
                hv[0] = (_Float16)a0; hv[1] = (_Float16)a1;
                hv[2] = (_Float16)a2; hv[3] = (_Float16)a3;
                *(h4*)(&At[m][n0]) = hv;
            }
        }
        if (dflag && lq == 0)            // n==256 lives in reg 0 of lq==0 lanes
            dval[m] = accd[mt][0] + dbias;
    }
    __syncthreads();   // At ready for next layer
}

__global__ __launch_bounds__(256, 2)
void ffmlp_kernel(const float* __restrict__ mean, const float* __restrict__ cov,
                  const int* __restrict__ decayscale,
                  const _Float16* __restrict__ wws, const float* __restrict__ bws,
                  const float* __restrict__ bc_out,
                  float* __restrict__ out, int N)
{
    __shared__ __align__(16) _Float16 At[128][KPAD];
    __shared__ float dval[128];

    const int t = threadIdx.x;
    const int wid = t >> 6, lane = t & 63;
    const int r = wid >> 1, c = wid & 1;
    const int lrow = lane & 31, lq = lane >> 5;
    const int rbase = r * 64;
    const int p0 = blockIdx.x * 128;

    // ---- Fourier embedding (fp32 math, fp16 store). 2 threads per point. ----
    {
        const int m = t >> 1, hf = t & 1;
        const long pt = (long)p0 + m;
        float x0 = 0.f, x1 = 0.f, x2 = 0.f, v0 = 0.f, v1 = 0.f, v2 = 0.f;
        if (pt < N) {
            x0 = mean[pt * 3 + 0]; x1 = mean[pt * 3 + 1]; x2 = mean[pt * 3 + 2];
            v0 = cov[pt * 9 + 0];  v1 = cov[pt * 9 + 4];  v2 = cov[pt * 9 + 8];
        }
        const float dec = (float)(*decayscale);
        if (hf == 0) {
            At[m][0] = (_Float16)x0; At[m][1] = (_Float16)x1; At[m][2] = (_Float16)x2;
            for (int k = 75; k < 86; ++k) At[m][k] = (_Float16)0.f;
        } else {
            for (int k = 86; k < 96; ++k) At[m][k] = (_Float16)0.f;
        }
        const float xs[3] = {x0, x1, x2}, vs[3] = {v0, v1, v2};
#pragma unroll
        for (int fi = 0; fi < 6; ++fi) {
            const int f = hf * 6 + fi;
            const float fs = (float)(1 << f);
            const float wcl = fminf(fmaxf(dec - (float)f, 0.f), 1.f);
            const float win = 0.5f * (1.f - cosf(wcl * PI_F));
#pragma unroll
            for (int d = 0; d < 3; ++d) {
                const float xb = xs[d] * fs;
                const float att = expf(-0.5f * vs[d] * fs * fs) * win;
                float s, co;
                sincosf(xb, &s, &co);
                At[m][3 + 6 * f + d] = (_Float16)(s * att);
                At[m][6 + 6 * f + d] = (_Float16)(co * att);
            }
        }
    }
    __syncthreads();

    // ---- density MLP ----
    dense<6, 4, true, 96>(At, wws + OFF_DIN, bws + B_DIN, rbase, c * 128, lrow, lq, false, dval, 0.f);
#pragma unroll 1
    for (int i = 0; i < 6; ++i)
        dense<16, 4, true, 256>(At, wws + OFF_DHID + i * 65536, bws + B_DHID + i * 256,
                                rbase, c * 128, lrow, lq, false, dval, 0.f);
    // features (no relu) + density scalar via extra ntile on c==1 waves
    {
        const float dbias = bws[B_FEAT + 256];
        dense<16, 4, false, 256>(At, wws + OFF_DOUT, bws + B_FEAT,
                                 rbase, c * 128, lrow, lq, (c == 1), dval, dbias);
    }

    // ---- color MLP ----
    dense<16, 2, true, 256>(At, wws + OFF_CIN, bws + B_CIN, rbase, c * 64, lrow, lq, false, dval, 0.f);
#pragma unroll 1
    for (int i = 0; i < 2; ++i)
        dense<8, 2, true, 128>(At, wws + OFF_CHID + i * 16384, bws + B_CHID + i * 128,
                               rbase, c * 64, lrow, lq, false, dval, 0.f);

    // ---- output layer: 128 -> 16 (rgb in cols 0..2), only c==0 waves ----
    if (c == 0) {
        f32x16 acc[2];
#pragma unroll
        for (int mt = 0; mt < 2; ++mt)
#pragma unroll
            for (int j = 0; j < 16; ++j) acc[mt][j] = 0.f;
        const _Float16* wco = wws + OFF_COUT + (size_t)lrow * 128 + lq * 8;
#pragma unroll
        for (int kt = 0; kt < 8; ++kt) {
            const int koff = kt * 16 + lq * 8;
            h8 wf = *(const h8*)(wco + kt * 16);
#pragma unroll
            for (int mt = 0; mt < 2; ++mt) {
                h8 af = *(const h8*)(&At[rbase + mt * 32 + lrow][koff]);
                acc[mt] = __builtin_amdgcn_mfma_f32_32x32x16_f16(wf, af, acc[mt], 0, 0, 0);
            }
        }
        const float bc0 = bc_out[0], bc1 = bc_out[1], bc2 = bc_out[2];
        if (lq == 0) {
#pragma unroll
            for (int mt = 0; mt < 2; ++mt) {
                const int m = rbase + mt * 32 + lrow;
                const long pt = (long)p0 + m;
                if (pt < N) {
                    float4 o;
                    o.x = acc[mt][0] + bc0;   // n=0: reg0, lq0
                    o.y = acc[mt][1] + bc1;   // n=1: reg1, lq0
                    o.z = acc[mt][2] + bc2;   // n=2: reg2, lq0
                    o.w = dval[m];
                    *(float4*)(out + pt * 4) = o;
                }
            }
        }
    }
}

extern "C" void kernel_launch(void* const* d_in, const int* in_sizes, int n_in,
                              void* d_out, int out_size, void* d_ws, size_t ws_size,
                              hipStream_t stream)
{
    const float* mean   = (const float*)d_in[0];
    const float* cov    = (const float*)d_in[1];
    const float* Wd_in  = (const float*)d_in[2];
    const float* bd_in  = (const float*)d_in[3];
    const float* Wd_hid = (const float*)d_in[4];
    const float* bd_hid = (const float*)d_in[5];
    const float* Wd_out = (const float*)d_in[6];
    const float* bd_out = (const float*)d_in[7];
    const float* Wc_in  = (const float*)d_in[8];
    const float* bc_in  = (const float*)d_in[9];
    const float* Wc_hid = (const float*)d_in[10];
    const float* bc_hid = (const float*)d_in[11];
    const float* Wc_out = (const float*)d_in[12];
    const float* bc_out = (const float*)d_in[13];
    const int*   decay  = (const int*)d_in[14];

    _Float16* wws = (_Float16*)d_ws;
    float*    bws = (float*)((char*)d_ws + (size_t)W_TOTAL * 2);

    const int N = in_sizes[0] / 3;     // 262144 points

    const int prep_blocks = (PREP_TOTAL + 255) / 256;
    prep_kernel<<<prep_blocks, 256, 0, stream>>>(Wd_in, Wd_hid, Wd_out, Wc_in, Wc_hid, Wc_out,
                                                 bd_in, bd_hid, bd_out, bc_in, bc_hid, wws, bws);

    const int blocks = (N + 127) / 128;
    ffmlp_kernel<<<blocks, 256, 0, stream>>>(mean, cov, decay, wws, bws, bc_out, (float*)d_out, N);
}